// Round 1
// baseline (638.764 us; speedup 1.0000x reference)
//
#include <hip/hip_runtime.h>
#include <hip/hip_bf16.h>
#include <stdint.h>

#define BATCH 8
#define SEQ   4096
#define EMB   1024
#define HD    128

typedef __attribute__((ext_vector_type(8))) short short8;
typedef __attribute__((ext_vector_type(4))) float f32x4;

__device__ inline unsigned short f2bf(float f) {
    union { float f; unsigned int u; } c; c.f = f;
    unsigned int u = c.u;
    unsigned int r = (u + 0x7fffu + ((u >> 16) & 1u)) >> 16;
    return (unsigned short)r;
}

// ---------------------------------------------------------------------------
// prep: pack Wq|Wk|Wv -> bf16 Wt[384][1024] (n-major, k contiguous), bias[384]
// ---------------------------------------------------------------------------
__global__ __launch_bounds__(256) void prep_kernel(
    const float* __restrict__ Wq, const float* __restrict__ bq,
    const float* __restrict__ Wk, const float* __restrict__ bk,
    const float* __restrict__ Wv, const float* __restrict__ bv,
    unsigned short* __restrict__ wt, float* __restrict__ biasc)
{
    int idx = blockIdx.x * 256 + threadIdx.x;      // < 384*1024
    int n   = idx >> 10;
    int kk  = idx & 1023;
    int sel = n >> 7;
    int h   = n & 127;
    const float* W = (sel == 0) ? Wq : (sel == 1) ? Wk : Wv;
    wt[idx] = f2bf(W[kk * HD + h]);
    if (idx < 384) {
        int s2 = idx >> 7;
        const float* bp = (s2 == 0) ? bq : (s2 == 1) ? bk : bv;
        biasc[idx] = bp[idx & 127];
    }
}

// ---------------------------------------------------------------------------
// gemm_qkv: C[m][n] = x[m][k] * Wt[n][k] + bias ; 128x128 tile per block
// sel 0 -> q (pre-scaled, bf16 [m][h]); sel 1 -> k (bf16 [m][h]);
// sel 2 -> v transposed (bf16 vt[b][h][t])
// ---------------------------------------------------------------------------
__global__ __launch_bounds__(256) void gemm_qkv(
    const float* __restrict__ x, const unsigned short* __restrict__ wt,
    const float* __restrict__ biasc,
    unsigned short* __restrict__ q, unsigned short* __restrict__ kOut,
    unsigned short* __restrict__ vt)
{
    const int sel = blockIdx.x;        // 0..2
    const int m0  = blockIdx.y * 128;  // 0..32640
    const int tid = threadIdx.x;
    const int wave = tid >> 6, lane = tid & 63;
    const int quad = lane >> 4, l15 = lane & 15;
    const int wx = wave & 1, wy = wave >> 1;

    __shared__ unsigned short As[128][40];   // +8 pad breaks bank aliasing
    __shared__ unsigned short Bs[128][32];   // global_load_lds dest (no pad)

    f32x4 acc[4][4];
#pragma unroll
    for (int i = 0; i < 4; ++i)
#pragma unroll
        for (int j = 0; j < 4; ++j)
            acc[i][j] = (f32x4){0.f, 0.f, 0.f, 0.f};

    const unsigned short* wbase = wt + (size_t)(sel * 128) * EMB;

    for (int kt = 0; kt < EMB / 32; ++kt) {
        const int k0 = kt * 32;
        // ---- stage A (fp32 -> bf16 via VGPRs) ----
#pragma unroll
        for (int i = 0; i < 4; ++i) {
            int e   = tid + i * 256;       // 0..1023
            int row = e >> 3;              // 0..127
            int kc  = (e & 7) * 4;         // 0..28
            float4 xv = *(const float4*)(x + (size_t)(m0 + row) * EMB + k0 + kc);
            union { unsigned short us[4]; uint2 v; } pk;
            pk.us[0] = f2bf(xv.x); pk.us[1] = f2bf(xv.y);
            pk.us[2] = f2bf(xv.z); pk.us[3] = f2bf(xv.w);
            *(uint2*)&As[row][kc] = pk.v;
        }
        // ---- stage B via async global->LDS (16B/lane) ----
#pragma unroll
        for (int c = 0; c < 2; ++c) {
            int chunk = wave * 2 + c;                  // 0..7
            int n = chunk * 16 + (lane >> 2);          // row of Bs
            const unsigned short* gp = wbase + (size_t)n * EMB + k0 + (lane & 3) * 8;
            __builtin_amdgcn_global_load_lds(
                (const __attribute__((address_space(1))) void*)gp,
                (__attribute__((address_space(3))) void*)&Bs[chunk * 16][0],
                16, 0, 0);
        }
        __syncthreads();
        short8 af[4], bfr[4];
#pragma unroll
        for (int mi = 0; mi < 4; ++mi)
            af[mi] = *(const short8*)&As[wy * 64 + mi * 16 + l15][quad * 8];
#pragma unroll
        for (int ni = 0; ni < 4; ++ni)
            bfr[ni] = *(const short8*)&Bs[wx * 64 + ni * 16 + l15][quad * 8];
#pragma unroll
        for (int mi = 0; mi < 4; ++mi)
#pragma unroll
            for (int ni = 0; ni < 4; ++ni)
                acc[mi][ni] = __builtin_amdgcn_mfma_f32_16x16x32_bf16(
                    af[mi], bfr[ni], acc[mi][ni], 0, 0, 0);
        __syncthreads();
    }

    // ---- epilogue ----
    const float qscale = 0.08838834764831845f * 1.4426950408889634f; // 1/sqrt(128)*log2e
    const int bb = m0 >> 12;         // batch index
    const int t0 = m0 & 4095;        // t within batch
#pragma unroll
    for (int mi = 0; mi < 4; ++mi) {
#pragma unroll
        for (int ni = 0; ni < 4; ++ni) {
            int c = wx * 64 + ni * 16 + l15;
            float bias = biasc[sel * 128 + c];
            int rbase = wy * 64 + mi * 16 + quad * 4;
            if (sel == 0) {
#pragma unroll
                for (int j = 0; j < 4; ++j) {
                    size_t m = (size_t)(m0 + rbase + j);
                    q[m * HD + c] = f2bf((acc[mi][ni][j] + bias) * qscale);
                }
            } else if (sel == 1) {
#pragma unroll
                for (int j = 0; j < 4; ++j) {
                    size_t m = (size_t)(m0 + rbase + j);
                    kOut[m * HD + c] = f2bf(acc[mi][ni][j] + bias);
                }
            } else {
                union { unsigned short us[4]; uint2 v; } pk;
#pragma unroll
                for (int j = 0; j < 4; ++j)
                    pk.us[j] = f2bf(acc[mi][ni][j] + bias);
                *(uint2*)&vt[((size_t)(bb * 128 + c)) * SEQ + t0 + rbase] = pk.v;
            }
        }
    }
}

// ---------------------------------------------------------------------------
// attn: flash attention. Block = (q-tile of 128 rows, batch). 4 waves,
// each wave owns 32 q-rows. BN=128 keys per step.
// q is pre-scaled by (1/sqrt(128))*log2e -> softmax in base-2 (v_exp_f32).
// ---------------------------------------------------------------------------
__global__ __launch_bounds__(256, 1) void attn_kernel(
    const unsigned short* __restrict__ q, const unsigned short* __restrict__ k,
    const unsigned short* __restrict__ vt, float* __restrict__ out)
{
    const int qt = blockIdx.x;   // 0..31
    const int b  = blockIdx.y;   // 0..7
    const int tid = threadIdx.x;
    const int wave = tid >> 6, lane = tid & 63;
    const int quad = lane >> 4, l15 = lane & 15;

    __shared__ unsigned short P[4][32][136];   // per-wave P tile, padded

    const int qm0 = qt * 128 + wave * 32;      // q row within batch
    const size_t qbase = (size_t)b * SEQ;
    const size_t vbase = (size_t)b * HD * SEQ; // vt[b][h][t]

    // Q fragments resident in registers (A-operand layout)
    short8 qf[2][4];
#pragma unroll
    for (int mi = 0; mi < 2; ++mi)
#pragma unroll
        for (int kh = 0; kh < 4; ++kh)
            qf[mi][kh] = *(const short8*)(q + (qbase + qm0 + mi * 16 + l15) * HD + kh * 32 + quad * 8);

    f32x4 o[2][8];
#pragma unroll
    for (int mi = 0; mi < 2; ++mi)
#pragma unroll
        for (int hi = 0; hi < 8; ++hi)
            o[mi][hi] = (f32x4){0.f, 0.f, 0.f, 0.f};
    f32x4 m_r[2], l_r[2];
#pragma unroll
    for (int mi = 0; mi < 2; ++mi) {
        m_r[mi] = (f32x4){-1e30f, -1e30f, -1e30f, -1e30f};
        l_r[mi] = (f32x4){0.f, 0.f, 0.f, 0.f};
    }

    for (int kt = 0; kt <= qt; ++kt) {
        const int key0 = kt * 128;
        // ---- S = Q K^T (128-key tile) ----
        f32x4 s[2][8];
#pragma unroll
        for (int mi = 0; mi < 2; ++mi)
#pragma unroll
            for (int ni = 0; ni < 8; ++ni)
                s[mi][ni] = (f32x4){0.f, 0.f, 0.f, 0.f};
#pragma unroll
        for (int kh = 0; kh < 4; ++kh) {
            short8 bfr[8];
#pragma unroll
            for (int ni = 0; ni < 8; ++ni)
                bfr[ni] = *(const short8*)(k + (qbase + key0 + ni * 16 + l15) * HD + kh * 32 + quad * 8);
#pragma unroll
            for (int ni = 0; ni < 8; ++ni) {
                s[0][ni] = __builtin_amdgcn_mfma_f32_16x16x32_bf16(qf[0][kh], bfr[ni], s[0][ni], 0, 0, 0);
                s[1][ni] = __builtin_amdgcn_mfma_f32_16x16x32_bf16(qf[1][kh], bfr[ni], s[1][ni], 0, 0, 0);
            }
        }
        // ---- causal mask (diagonal tile only) ----
        if (kt == qt) {
#pragma unroll
            for (int mi = 0; mi < 2; ++mi)
#pragma unroll
                for (int ni = 0; ni < 8; ++ni)
#pragma unroll
                    for (int j = 0; j < 4; ++j) {
                        int t   = qm0 + mi * 16 + quad * 4 + j;
                        int key = key0 + ni * 16 + l15;
                        if (key > t) s[mi][ni][j] = -1e30f;
                    }
        }
        // ---- online softmax update ----
#pragma unroll
        for (int mi = 0; mi < 2; ++mi) {
            f32x4 mnew;
#pragma unroll
            for (int j = 0; j < 4; ++j) {
                float mx = s[mi][0][j];
#pragma unroll
                for (int ni = 1; ni < 8; ++ni) mx = fmaxf(mx, s[mi][ni][j]);
                mx = fmaxf(mx, __shfl_xor(mx, 1));
                mx = fmaxf(mx, __shfl_xor(mx, 2));
                mx = fmaxf(mx, __shfl_xor(mx, 4));
                mx = fmaxf(mx, __shfl_xor(mx, 8));
                mnew[j] = fmaxf(m_r[mi][j], mx);
            }
            f32x4 alpha;
#pragma unroll
            for (int j = 0; j < 4; ++j)
                alpha[j] = __builtin_amdgcn_exp2f(m_r[mi][j] - mnew[j]);
            m_r[mi] = mnew;
            f32x4 rs = (f32x4){0.f, 0.f, 0.f, 0.f};
#pragma unroll
            for (int ni = 0; ni < 8; ++ni)
#pragma unroll
                for (int j = 0; j < 4; ++j) {
                    float p = __builtin_amdgcn_exp2f(s[mi][ni][j] - mnew[j]);
                    rs[j] += p;
                    P[wave][mi * 16 + quad * 4 + j][ni * 16 + l15] = f2bf(p);
                }
#pragma unroll
            for (int j = 0; j < 4; ++j) {
                float t = rs[j];
                t += __shfl_xor(t, 1);
                t += __shfl_xor(t, 2);
                t += __shfl_xor(t, 4);
                t += __shfl_xor(t, 8);
                rs[j] = t;
            }
            l_r[mi] = alpha * l_r[mi] + rs;
#pragma unroll
            for (int hi = 0; hi < 8; ++hi) o[mi][hi] *= alpha;
        }
        __syncthreads();   // P visible (also keeps waves in lockstep)
        // ---- O += P V  (P from LDS in A-layout, V^T from global) ----
#pragma unroll
        for (int sk = 0; sk < 4; ++sk) {
            short8 pa[2];
            pa[0] = *(const short8*)&P[wave][l15][sk * 32 + quad * 8];
            pa[1] = *(const short8*)&P[wave][16 + l15][sk * 32 + quad * 8];
#pragma unroll
            for (int hi = 0; hi < 8; ++hi) {
                short8 vb = *(const short8*)(vt + vbase + (size_t)(hi * 16 + l15) * SEQ + key0 + sk * 32 + quad * 8);
                o[0][hi] = __builtin_amdgcn_mfma_f32_16x16x32_bf16(pa[0], vb, o[0][hi], 0, 0, 0);
                o[1][hi] = __builtin_amdgcn_mfma_f32_16x16x32_bf16(pa[1], vb, o[1][hi], 0, 0, 0);
            }
        }
        __syncthreads();   // protect P before next iteration's writes
    }

    // ---- epilogue: O / l ----
#pragma unroll
    for (int mi = 0; mi < 2; ++mi) {
        f32x4 inv;
#pragma unroll
        for (int j = 0; j < 4; ++j) inv[j] = 1.0f / l_r[mi][j];
#pragma unroll
        for (int hi = 0; hi < 8; ++hi)
#pragma unroll
            for (int j = 0; j < 4; ++j)
                out[(qbase + qm0 + mi * 16 + quad * 4 + j) * HD + hi * 16 + l15] =
                    o[mi][hi][j] * inv[j];
    }
}

// ---------------------------------------------------------------------------
extern "C" void kernel_launch(void* const* d_in, const int* in_sizes, int n_in,
                              void* d_out, int out_size, void* d_ws, size_t ws_size,
                              hipStream_t stream) {
    const float* x  = (const float*)d_in[0];
    const float* Wq = (const float*)d_in[1];
    const float* bq = (const float*)d_in[2];
    const float* Wk = (const float*)d_in[3];
    const float* bk = (const float*)d_in[4];
    const float* Wv = (const float*)d_in[5];
    const float* bv = (const float*)d_in[6];
    float* out = (float*)d_out;

    // workspace layout
    unsigned short* wt    = (unsigned short*)d_ws;                   // 384*1024*2 = 786432 B
    float*          biasc = (float*)((char*)d_ws + 786432);          // 1536 B
    unsigned short* qb    = (unsigned short*)((char*)d_ws + 787968); // 8.4 MB
    unsigned short* kb    = qb + (size_t)BATCH * SEQ * HD;
    unsigned short* vtb   = kb + (size_t)BATCH * SEQ * HD;

    prep_kernel<<<dim3(384 * 1024 / 256), 256, 0, stream>>>(Wq, bq, Wk, bk, Wv, bv, wt, biasc);
    gemm_qkv<<<dim3(3, 256), 256, 0, stream>>>(x, wt, biasc, qb, kb, vtb);
    attn_kernel<<<dim3(SEQ / 128, BATCH), 256, 0, stream>>>(qb, kb, vtb, out);
}

// Round 2
// 392.551 us; speedup vs baseline: 1.6272x; 1.6272x over previous
//
#include <hip/hip_runtime.h>
#include <hip/hip_bf16.h>
#include <stdint.h>

#define BATCH 8
#define SEQ   4096
#define EMB   1024
#define HD    128

typedef __attribute__((ext_vector_type(8))) short short8;
typedef __attribute__((ext_vector_type(4))) float f32x4;

__device__ inline unsigned short f2bf(float f) {
    union { float f; unsigned int u; } c; c.f = f;
    unsigned int u = c.u;
    unsigned int r = (u + 0x7fffu + ((u >> 16) & 1u)) >> 16;
    return (unsigned short)r;
}

// ---------------------------------------------------------------------------
// prep: pack Wq|Wk|Wv -> bf16 Wt[384][1024] (n-major, k contiguous), bias[384]
// ---------------------------------------------------------------------------
__global__ __launch_bounds__(256) void prep_kernel(
    const float* __restrict__ Wq, const float* __restrict__ bq,
    const float* __restrict__ Wk, const float* __restrict__ bk,
    const float* __restrict__ Wv, const float* __restrict__ bv,
    unsigned short* __restrict__ wt, float* __restrict__ biasc)
{
    int idx = blockIdx.x * 256 + threadIdx.x;      // < 384*1024
    int n   = idx >> 10;
    int kk  = idx & 1023;
    int sel = n >> 7;
    int h   = n & 127;
    const float* W = (sel == 0) ? Wq : (sel == 1) ? Wk : Wv;
    wt[idx] = f2bf(W[kk * HD + h]);
    if (idx < 384) {
        int s2 = idx >> 7;
        const float* bp = (s2 == 0) ? bq : (s2 == 1) ? bk : bv;
        biasc[idx] = bp[idx & 127];
    }
}

// ---------------------------------------------------------------------------
// gemm_qkv (fused): C[m][0..383] = x[m][:] * Wt[n][:] + bias, one x read.
// 128 rows x 384 cols per block, 512 threads (8 waves: 2 row-halves x 4
// col-chunks of 96). cols 0..127 -> q (pre-scaled), 128..255 -> k,
// 256..383 -> v transposed (vt[b][h][t]).
// ---------------------------------------------------------------------------
__global__ __launch_bounds__(512, 2) void gemm_qkv(
    const float* __restrict__ x, const unsigned short* __restrict__ wt,
    const float* __restrict__ biasc,
    unsigned short* __restrict__ q, unsigned short* __restrict__ kOut,
    unsigned short* __restrict__ vt)
{
    const int m0  = blockIdx.x * 128;
    const int tid = threadIdx.x;
    const int wave = tid >> 6, lane = tid & 63;
    const int quad = lane >> 4, l15 = lane & 15;
    const int wy = wave & 1;        // row half (64 rows)
    const int wxc = wave >> 1;      // col chunk (96 cols = 6 frags)

    __shared__ unsigned short As[128][40];     // +8 pad
    __shared__ unsigned short Bs[384 * 32];    // [n][32], global_load_lds dest

    f32x4 acc[4][6];
#pragma unroll
    for (int i = 0; i < 4; ++i)
#pragma unroll
        for (int j = 0; j < 6; ++j)
            acc[i][j] = (f32x4){0.f, 0.f, 0.f, 0.f};

    for (int kt = 0; kt < EMB / 32; ++kt) {
        const int k0 = kt * 32;
        // ---- stage A (fp32 -> bf16 via VGPRs) : 128 rows x 32 k ----
#pragma unroll
        for (int i = 0; i < 2; ++i) {
            int e   = tid + i * 512;       // 0..1023
            int row = e >> 3;
            int kc  = (e & 7) * 4;
            float4 xv = *(const float4*)(x + (size_t)(m0 + row) * EMB + k0 + kc);
            union { unsigned short us[4]; uint2 v; } pk;
            pk.us[0] = f2bf(xv.x); pk.us[1] = f2bf(xv.y);
            pk.us[2] = f2bf(xv.z); pk.us[3] = f2bf(xv.w);
            *(uint2*)&As[row][kc] = pk.v;
        }
        // ---- stage B via async global->LDS: 384 rows x 32 k = 24KB ----
#pragma unroll
        for (int i = 0; i < 3; ++i) {
            int cid = i * 8 + wave;                  // 0..23, 16 rows each
            int n = cid * 16 + (lane >> 2);
            const unsigned short* gp = wt + (size_t)n * EMB + k0 + (lane & 3) * 8;
            __builtin_amdgcn_global_load_lds(
                (const __attribute__((address_space(1))) void*)gp,
                (__attribute__((address_space(3))) void*)&Bs[cid * 512],
                16, 0, 0);
        }
        __syncthreads();
        short8 af[4], bfr[6];
#pragma unroll
        for (int mi = 0; mi < 4; ++mi)
            af[mi] = *(const short8*)&As[wy * 64 + mi * 16 + l15][quad * 8];
#pragma unroll
        for (int ni = 0; ni < 6; ++ni)
            bfr[ni] = *(const short8*)&Bs[(wxc * 96 + ni * 16 + l15) * 32 + quad * 8];
#pragma unroll
        for (int mi = 0; mi < 4; ++mi)
#pragma unroll
            for (int ni = 0; ni < 6; ++ni)
                acc[mi][ni] = __builtin_amdgcn_mfma_f32_16x16x32_bf16(
                    af[mi], bfr[ni], acc[mi][ni], 0, 0, 0);
        __syncthreads();
    }

    // ---- epilogue ----
    const float qscale = 0.08838834764831845f * 1.4426950408889634f; // 1/sqrt(128)*log2e
    const int bb = m0 >> 12;
    const int t0 = m0 & 4095;
#pragma unroll
    for (int mi = 0; mi < 4; ++mi) {
#pragma unroll
        for (int ni = 0; ni < 6; ++ni) {
            int cbase = wxc * 96 + ni * 16;      // 16-aligned, sel uniform per frag
            int sel = cbase >> 7;
            int cc = cbase + l15;
            int h = cc & 127;
            float bias = biasc[cc];
            int rbase = wy * 64 + mi * 16 + quad * 4;
            if (sel == 0) {
#pragma unroll
                for (int j = 0; j < 4; ++j) {
                    size_t m = (size_t)(m0 + rbase + j);
                    q[m * HD + h] = f2bf((acc[mi][ni][j] + bias) * qscale);
                }
            } else if (sel == 1) {
#pragma unroll
                for (int j = 0; j < 4; ++j) {
                    size_t m = (size_t)(m0 + rbase + j);
                    kOut[m * HD + h] = f2bf(acc[mi][ni][j] + bias);
                }
            } else {
                union { unsigned short us[4]; uint2 v; } pk;
#pragma unroll
                for (int j = 0; j < 4; ++j)
                    pk.us[j] = f2bf(acc[mi][ni][j] + bias);
                *(uint2*)&vt[((size_t)(bb * 128 + h)) * SEQ + t0 + rbase] = pk.v;
            }
        }
    }
}

// ---------------------------------------------------------------------------
// attn: flash attention. Block = 64 Q rows; 4 waves x 16 rows. BN=64 keys.
// Grid = 512 blocks, LPT order (heaviest qt first across batches).
// K and V tiles staged once per block in LDS via global_load_lds.
// q pre-scaled by (1/sqrt(128))*log2e -> base-2 softmax.
// ---------------------------------------------------------------------------
__global__ __launch_bounds__(256, 3) void attn_kernel(
    const unsigned short* __restrict__ q, const unsigned short* __restrict__ k,
    const unsigned short* __restrict__ vt, float* __restrict__ out)
{
    const int rank = blockIdx.x;          // 0..511
    const int qt   = 63 - (rank >> 3);    // heavy tiles dispatched first
    const int b    = rank & 7;
    const int tid  = threadIdx.x;
    const int wave = tid >> 6, lane = tid & 63;
    const int quad = lane >> 4, l15 = lane & 15;

    __shared__ unsigned short Ks[4 * 64 * 32];   // [kh][key][32]  16KB
    __shared__ unsigned short Vs[2 * 128 * 32];  // [sk][h][32]    16KB
    __shared__ unsigned short P[4][16][72];      // per-wave P      9KB

    const int qm0 = qt * 64 + wave * 16;         // this wave's q rows
    const size_t qbase = (size_t)b * SEQ;
    const size_t vbase = (size_t)b * HD * SEQ;   // vt[b][h][t]

    // Q fragments resident (A-layout)
    short8 qf[4];
#pragma unroll
    for (int kh = 0; kh < 4; ++kh)
        qf[kh] = *(const short8*)(q + (qbase + qm0 + l15) * HD + kh * 32 + quad * 8);

    f32x4 o[8];
#pragma unroll
    for (int hi = 0; hi < 8; ++hi) o[hi] = (f32x4){0.f, 0.f, 0.f, 0.f};
    f32x4 m_r = (f32x4){-1e30f, -1e30f, -1e30f, -1e30f};
    f32x4 l_r = (f32x4){0.f, 0.f, 0.f, 0.f};

    for (int kt = 0; kt <= qt; ++kt) {
        const int key0 = kt * 64;
        __syncthreads();   // protect Ks/Vs from overwrite (prior reads done)
        // ---- stage K tile: 4 chunks/wave x 1KB ----
#pragma unroll
        for (int i = 0; i < 4; ++i) {
            int cid = i * 4 + wave;                      // 0..15
            int kh = cid >> 2;
            int kr = (cid & 3) * 16 + (lane >> 2);
            const unsigned short* gp =
                k + (qbase + key0 + kr) * HD + kh * 32 + (lane & 3) * 8;
            __builtin_amdgcn_global_load_lds(
                (const __attribute__((address_space(1))) void*)gp,
                (__attribute__((address_space(3))) void*)&Ks[cid * 512],
                16, 0, 0);
        }
        // ---- stage V tile (from vt[b][h][t]) ----
#pragma unroll
        for (int i = 0; i < 4; ++i) {
            int cid = i * 4 + wave;                      // 0..15
            int sk = cid >> 3;
            int h  = (cid & 7) * 16 + (lane >> 2);
            const unsigned short* gp =
                vt + vbase + (size_t)h * SEQ + key0 + sk * 32 + (lane & 3) * 8;
            __builtin_amdgcn_global_load_lds(
                (const __attribute__((address_space(1))) void*)gp,
                (__attribute__((address_space(3))) void*)&Vs[cid * 512],
                16, 0, 0);
        }
        __syncthreads();   // staging complete

        // ---- S = Q K^T ----
        f32x4 s[4];
#pragma unroll
        for (int ni = 0; ni < 4; ++ni) s[ni] = (f32x4){0.f, 0.f, 0.f, 0.f};
#pragma unroll
        for (int kh = 0; kh < 4; ++kh) {
#pragma unroll
            for (int ni = 0; ni < 4; ++ni) {
                short8 bfr = *(const short8*)&Ks[kh * 2048 + (ni * 16 + l15) * 32 + quad * 8];
                s[ni] = __builtin_amdgcn_mfma_f32_16x16x32_bf16(qf[kh], bfr, s[ni], 0, 0, 0);
            }
        }
        // ---- causal mask (diagonal tile only) ----
        if (kt == qt) {
#pragma unroll
            for (int ni = 0; ni < 4; ++ni)
#pragma unroll
                for (int j = 0; j < 4; ++j) {
                    int t   = qm0 + quad * 4 + j;
                    int key = key0 + ni * 16 + l15;
                    if (key > t) s[ni][j] = -1e30f;
                }
        }
        // ---- online softmax ----
        f32x4 mnew;
#pragma unroll
        for (int j = 0; j < 4; ++j) {
            float mx = fmaxf(fmaxf(s[0][j], s[1][j]), fmaxf(s[2][j], s[3][j]));
            mx = fmaxf(mx, __shfl_xor(mx, 1));
            mx = fmaxf(mx, __shfl_xor(mx, 2));
            mx = fmaxf(mx, __shfl_xor(mx, 4));
            mx = fmaxf(mx, __shfl_xor(mx, 8));
            mnew[j] = fmaxf(m_r[j], mx);
        }
        f32x4 alpha;
#pragma unroll
        for (int j = 0; j < 4; ++j)
            alpha[j] = __builtin_amdgcn_exp2f(m_r[j] - mnew[j]);
        m_r = mnew;
        f32x4 rs = (f32x4){0.f, 0.f, 0.f, 0.f};
#pragma unroll
        for (int ni = 0; ni < 4; ++ni)
#pragma unroll
            for (int j = 0; j < 4; ++j) {
                float p = __builtin_amdgcn_exp2f(s[ni][j] - mnew[j]);
                rs[j] += p;
                P[wave][quad * 4 + j][ni * 16 + l15] = f2bf(p);
            }
#pragma unroll
        for (int j = 0; j < 4; ++j) {
            float t = rs[j];
            t += __shfl_xor(t, 1);
            t += __shfl_xor(t, 2);
            t += __shfl_xor(t, 4);
            t += __shfl_xor(t, 8);
            rs[j] = t;
        }
        l_r = alpha * l_r + rs;
#pragma unroll
        for (int hi = 0; hi < 8; ++hi) o[hi] *= alpha;

        // ---- O += P V (P is wave-private LDS; no barrier needed) ----
#pragma unroll
        for (int sk = 0; sk < 2; ++sk) {
            short8 pa = *(const short8*)&P[wave][l15][sk * 32 + quad * 8];
#pragma unroll
            for (int hi = 0; hi < 8; ++hi) {
                short8 vb = *(const short8*)&Vs[sk * 4096 + (hi * 16 + l15) * 32 + quad * 8];
                o[hi] = __builtin_amdgcn_mfma_f32_16x16x32_bf16(pa, vb, o[hi], 0, 0, 0);
            }
        }
    }

    // ---- epilogue: O / l ----
    f32x4 inv;
#pragma unroll
    for (int j = 0; j < 4; ++j) inv[j] = 1.0f / l_r[j];
#pragma unroll
    for (int hi = 0; hi < 8; ++hi)
#pragma unroll
        for (int j = 0; j < 4; ++j)
            out[(qbase + qm0 + quad * 4 + j) * HD + hi * 16 + l15] = o[hi][j] * inv[j];
}

// ---------------------------------------------------------------------------
extern "C" void kernel_launch(void* const* d_in, const int* in_sizes, int n_in,
                              void* d_out, int out_size, void* d_ws, size_t ws_size,
                              hipStream_t stream) {
    const float* x  = (const float*)d_in[0];
    const float* Wq = (const float*)d_in[1];
    const float* bq = (const float*)d_in[2];
    const float* Wk = (const float*)d_in[3];
    const float* bk = (const float*)d_in[4];
    const float* Wv = (const float*)d_in[5];
    const float* bv = (const float*)d_in[6];
    float* out = (float*)d_out;

    // workspace layout
    unsigned short* wt    = (unsigned short*)d_ws;                   // 786432 B
    float*          biasc = (float*)((char*)d_ws + 786432);          // 1536 B
    unsigned short* qb    = (unsigned short*)((char*)d_ws + 787968); // 8.4 MB each
    unsigned short* kb    = qb + (size_t)BATCH * SEQ * HD;
    unsigned short* vtb   = kb + (size_t)BATCH * SEQ * HD;

    prep_kernel<<<dim3(384 * 1024 / 256), 256, 0, stream>>>(Wq, bq, Wk, bk, Wv, bv, wt, biasc);
    gemm_qkv<<<dim3(256), 512, 0, stream>>>(x, wt, biasc, qb, kb, vtb);
    attn_kernel<<<dim3(512), 256, 0, stream>>>(qb, kb, vtb, out);
}